// Round 1
// baseline (1061.400 us; speedup 1.0000x reference)
//
#include <hip/hip_runtime.h>
#include <hip/hip_bf16.h>
#include <stdint.h>

#define NIN  1024
#define NOUT 1024
#define NB   4096   // batch

#define BM 128
#define BN 128
#define BK 64

typedef float f32x4 __attribute__((ext_vector_type(4)));
typedef __bf16 bf16x8 __attribute__((ext_vector_type(8)));

typedef const __attribute__((address_space(1))) unsigned int* gp1_t;
typedef __attribute__((address_space(3))) unsigned int* lp3_t;

__device__ __forceinline__ void gload16(const void* g, void* l) {
    __builtin_amdgcn_global_load_lds((gp1_t)g, (lp3_t)l, 16, 0, 0);
}

__device__ __forceinline__ unsigned short f2bf(float f) {
    __bf16 h = (__bf16)f;
    return __builtin_bit_cast(unsigned short, h);
}

// ---- prep: x (NB x NIN f32) -> bf16 ----
__global__ void cvt_x_kernel(const float* __restrict__ x, unsigned short* __restrict__ xb) {
    int i = blockIdx.x * blockDim.x + threadIdx.x;   // float4 index, exact grid
    f32x4 v = reinterpret_cast<const f32x4*>(x)[i];
    ushort4 o;
    o.x = f2bf(v.x); o.y = f2bf(v.y); o.z = f2bf(v.z); o.w = f2bf(v.w);
    reinterpret_cast<ushort4*>(xb)[i] = o;
}

// ---- prep: bias[s,o] = b_mu[o] + exp(b_ls[o]) * r2[s,o] ----
__global__ void bias_kernel(const float* __restrict__ bmu, const float* __restrict__ bls,
                            const float* __restrict__ r2, float* __restrict__ bias, int total) {
    int i = blockIdx.x * blockDim.x + threadIdx.x;
    if (i < total) {
        int o = i & (NOUT - 1);
        bias[i] = bmu[o] + __expf(bls[o]) * r2[i];
    }
}

// ---- prep: W chunk bf16: wb[c,o,i] = w_mu[o,i] + exp(w_ls[o,i]) * r1[s0+c,o,i] ----
__global__ void build_w_kernel(const float* __restrict__ wmu, const float* __restrict__ wls,
                               const float* __restrict__ r1, unsigned short* __restrict__ wb,
                               int s0) {
    int idx = blockIdx.x * blockDim.x + threadIdx.x;   // float4 index within chunk
    int i4 = idx & (262143);        // NOUT*NIN/4 per sample = 2^18
    int c  = idx >> 18;
    f32x4 mu = reinterpret_cast<const f32x4*>(wmu)[i4];
    f32x4 ls = reinterpret_cast<const f32x4*>(wls)[i4];
    const f32x4* r1p = reinterpret_cast<const f32x4*>(r1 + ((size_t)(s0 + c) << 20));
    f32x4 r = r1p[i4];
    ushort4 o;
    o.x = f2bf(mu.x + __expf(ls.x) * r.x);
    o.y = f2bf(mu.y + __expf(ls.y) * r.y);
    o.z = f2bf(mu.z + __expf(ls.z) * r.z);
    o.w = f2bf(mu.w + __expf(ls.w) * r.w);
    reinterpret_cast<ushort4*>(wb)[idx] = o;
}

// ---- main GEMM: out[s0+c, m, o] = xb(M=NB,K) * wb(N=sc*NOUT,K)^T + bias ----
__launch_bounds__(256)
__global__ void gemm_kernel(const unsigned short* __restrict__ xb,
                            const unsigned short* __restrict__ wb,
                            const float* __restrict__ bias,
                            float* __restrict__ out, int s0) {
    __shared__ __align__(16) unsigned short lds[BM * BK + BN * BK]; // 16KB A + 16KB B
    const int tid  = threadIdx.x;
    const int lane = tid & 63;
    const int wv   = tid >> 6;          // 0..3
    const int wr   = wv >> 1, wc = wv & 1;
    const int m0   = blockIdx.x * BM;
    const int n0   = blockIdx.y * BN;   // within chunk

    f32x4 acc[4][4] = {};

    for (int kt = 0; kt < NIN / BK; ++kt) {
        __syncthreads();
        #pragma unroll
        for (int j = 0; j < 8; ++j) {
            int lin = j * 256 + tid;          // 16B chunk 0..2047 (A:0..1023, B:1024..2047)
            int e   = (lin & 1023) * 8;       // bf16 element offset in tile
            int row = e >> 6;                 // /BK
            int col = e & (BK - 1);
            const unsigned short* src;
            if (lin < 1024)
                src = xb + (size_t)(m0 + row) * NIN + kt * BK + col;
            else
                src = wb + (size_t)(n0 + row) * NIN + kt * BK + col;
            gload16(src, (void*)((char*)lds + (size_t)lin * 16));
        }
        __syncthreads();

        const unsigned short* As = lds;
        const unsigned short* Bs = lds + BM * BK;
        #pragma unroll
        for (int kk = 0; kk < BK / 32; ++kk) {
            bf16x8 af[4], bfr[4];
            int krd = kk * 32 + (lane >> 4) * 8;
            #pragma unroll
            for (int i = 0; i < 4; ++i)
                af[i] = *reinterpret_cast<const bf16x8*>(&As[(wr * 64 + i * 16 + (lane & 15)) * BK + krd]);
            #pragma unroll
            for (int i = 0; i < 4; ++i)
                bfr[i] = *reinterpret_cast<const bf16x8*>(&Bs[(wc * 64 + i * 16 + (lane & 15)) * BK + krd]);
            #pragma unroll
            for (int mb = 0; mb < 4; ++mb)
                #pragma unroll
                for (int nb = 0; nb < 4; ++nb)
                    acc[mb][nb] = __builtin_amdgcn_mfma_f32_16x16x32_bf16(af[mb], bfr[nb], acc[mb][nb], 0, 0, 0);
        }
    }

    // epilogue: bias add + f32 store. C/D map: col = lane&15, row = (lane>>4)*4 + reg.
    int c     = n0 >> 10;                       // sample within chunk (BN divides NOUT)
    int obase = (n0 & 1023) + wc * 64 + (lane & 15);
    int s     = s0 + c;
    float bv[4];
    #pragma unroll
    for (int nb = 0; nb < 4; ++nb) bv[nb] = bias[s * NOUT + obase + nb * 16];
    float* outb = out + (size_t)s * NB * NOUT;
    int mrow0 = m0 + wr * 64 + (lane >> 4) * 4;
    #pragma unroll
    for (int mb = 0; mb < 4; ++mb)
        #pragma unroll
        for (int nb = 0; nb < 4; ++nb)
            #pragma unroll
            for (int i = 0; i < 4; ++i)
                outb[(size_t)(mrow0 + mb * 16 + i) * NOUT + obase + nb * 16] = acc[mb][nb][i] + bv[nb];
}

// ---- zero-scratch correctness fallback (only if ws_size is tiny) ----
__global__ void fused_fallback(const float* __restrict__ x, const float* __restrict__ wmu,
                               const float* __restrict__ wls, const float* __restrict__ r1,
                               const float* __restrict__ bmu, const float* __restrict__ bls,
                               const float* __restrict__ r2, float* __restrict__ out) {
    __shared__ float Xs[16][64];
    __shared__ float Ws[16][64];
    int b0 = blockIdx.x * 16, o0 = blockIdx.y * 16, s = blockIdx.z;
    int tb = threadIdx.x >> 4, to = threadIdx.x & 15;
    float acc = 0.f;
    for (int k0 = 0; k0 < NIN; k0 += 64) {
        __syncthreads();
        #pragma unroll
        for (int j = 0; j < 4; ++j) {
            int e = j * 256 + threadIdx.x;
            int r = e >> 6, cc = e & 63;
            Xs[r][cc] = x[(size_t)(b0 + r) * NIN + k0 + cc];
            size_t wi = (size_t)(o0 + r) * NIN + k0 + cc;
            Ws[r][cc] = wmu[wi] + __expf(wls[wi]) * r1[(size_t)s * NIN * NOUT + wi];
        }
        __syncthreads();
        for (int k = 0; k < 64; ++k) acc += Xs[tb][k] * Ws[to][k];
    }
    int o = o0 + to;
    out[((size_t)s * NB + b0 + tb) * NOUT + o] = acc + bmu[o] + __expf(bls[o]) * r2[s * NOUT + o];
}

extern "C" void kernel_launch(void* const* d_in, const int* in_sizes, int n_in,
                              void* d_out, int out_size, void* d_ws, size_t ws_size,
                              hipStream_t stream) {
    const float* x   = (const float*)d_in[0];
    const float* wmu = (const float*)d_in[1];
    const float* wls = (const float*)d_in[2];
    const float* bmu = (const float*)d_in[3];
    const float* bls = (const float*)d_in[4];
    const float* r1  = (const float*)d_in[5];
    const float* r2  = (const float*)d_in[6];
    const int S = in_sizes[6] / NOUT;   // N_samples from r2 size
    float* out = (float*)d_out;

    size_t xb_bytes   = (size_t)NB * NIN * 2;
    size_t bias_bytes = (size_t)S * NOUT * 4;
    size_t per_sample = (size_t)NOUT * NIN * 2;

    if (ws_size < xb_bytes + bias_bytes + per_sample) {
        // not enough scratch: slow fused path, still correct
        dim3 g(NB / 16, NOUT / 16, S);
        fused_fallback<<<g, 256, 0, stream>>>(x, wmu, wls, r1, bmu, bls, r2, out);
        return;
    }

    char* ws = (char*)d_ws;
    unsigned short* xb  = (unsigned short*)ws;
    float* bias         = (float*)(ws + xb_bytes);
    unsigned short* wb  = (unsigned short*)(ws + xb_bytes + bias_bytes);

    size_t avail = ws_size - xb_bytes - bias_bytes;
    int SC = (int)(avail / per_sample);
    if (SC > S) SC = S;

    cvt_x_kernel<<<NB * NIN / 4 / 256, 256, 0, stream>>>(x, xb);
    bias_kernel<<<(S * NOUT + 255) / 256, 256, 0, stream>>>(bmu, bls, r2, bias, S * NOUT);

    for (int s0 = 0; s0 < S; s0 += SC) {
        int sc = (S - s0 < SC) ? (S - s0) : SC;
        build_w_kernel<<<sc * (NOUT * NIN / 4 / 256), 256, 0, stream>>>(wmu, wls, r1, wb, s0);
        dim3 g(NB / BM, sc * NOUT / BN);
        gemm_kernel<<<g, 256, 0, stream>>>(xb, wb, bias, out, s0);
    }
}

// Round 2
// 773.930 us; speedup vs baseline: 1.3714x; 1.3714x over previous
//
#include <hip/hip_runtime.h>
#include <hip/hip_bf16.h>
#include <stdint.h>
#include <type_traits>

#define NIN  1024
#define NOUT 1024
#define NB   4096   // batch

typedef float f32x4 __attribute__((ext_vector_type(4)));
typedef __bf16 bf16x8 __attribute__((ext_vector_type(8)));

typedef const __attribute__((address_space(1))) unsigned int* gp1_t;
typedef __attribute__((address_space(3))) unsigned int* lp3_t;

__device__ __forceinline__ void gload16(const void* g, void* l) {
    __builtin_amdgcn_global_load_lds((gp1_t)g, (lp3_t)l, 16, 0, 0);
}

__device__ __forceinline__ unsigned short f2bf(float f) {
    __bf16 h = (__bf16)f;
    return __builtin_bit_cast(unsigned short, h);
}

#define BAR  __builtin_amdgcn_s_barrier()
#define LGK0 do { asm volatile("s_waitcnt lgkmcnt(0)" ::: "memory"); __builtin_amdgcn_sched_barrier(0); } while (0)
#define VMW2 do { asm volatile("s_waitcnt vmcnt(2)" ::: "memory");   __builtin_amdgcn_sched_barrier(0); } while (0)
#define VMW0 do { asm volatile("s_waitcnt vmcnt(0)" ::: "memory");   __builtin_amdgcn_sched_barrier(0); } while (0)

// ---- prep: x (NB x NIN f32) -> bf16 ----
__global__ void cvt_x_kernel(const float* __restrict__ x, unsigned short* __restrict__ xb) {
    int i = blockIdx.x * blockDim.x + threadIdx.x;   // float4 index, exact grid
    f32x4 v = reinterpret_cast<const f32x4*>(x)[i];
    ushort4 o;
    o.x = f2bf(v.x); o.y = f2bf(v.y); o.z = f2bf(v.z); o.w = f2bf(v.w);
    reinterpret_cast<ushort4*>(xb)[i] = o;
}

// ---- prep: bias[s,o] = b_mu[o] + exp(b_ls[o]) * r2[s,o] ----
__global__ void bias_kernel(const float* __restrict__ bmu, const float* __restrict__ bls,
                            const float* __restrict__ r2, float* __restrict__ bias, int total) {
    int i = blockIdx.x * blockDim.x + threadIdx.x;
    if (i < total) {
        int o = i & (NOUT - 1);
        bias[i] = bmu[o] + __expf(bls[o]) * r2[i];
    }
}

// ---- prep: W chunk bf16: wb[c,o,i] = w_mu[o,i] + exp(w_ls[o,i]) * r1[s0+c,o,i] ----
__global__ void build_w_kernel(const float* __restrict__ wmu, const float* __restrict__ wls,
                               const float* __restrict__ r1, unsigned short* __restrict__ wb,
                               int s0) {
    int idx = blockIdx.x * blockDim.x + threadIdx.x;   // float4 index within chunk
    int i4 = idx & (262143);        // NOUT*NIN/4 per sample = 2^18
    int c  = idx >> 18;
    f32x4 mu = reinterpret_cast<const f32x4*>(wmu)[i4];
    f32x4 ls = reinterpret_cast<const f32x4*>(wls)[i4];
    const f32x4* r1p = reinterpret_cast<const f32x4*>(r1 + ((size_t)(s0 + c) << 20));
    f32x4 r = r1p[i4];
    ushort4 o;
    o.x = f2bf(mu.x + __expf(ls.x) * r.x);
    o.y = f2bf(mu.y + __expf(ls.y) * r.y);
    o.z = f2bf(mu.z + __expf(ls.z) * r.z);
    o.w = f2bf(mu.w + __expf(ls.w) * r.w);
    reinterpret_cast<ushort4*>(wb)[idx] = o;
}

// =====================================================================
// 256x256 8-phase GEMM: out[s, m, o] = xb(M=NB,K) * wb(N=sc*NOUT,K)^T + bias
// 8 waves (2M x 4N), BK=64, 2 K-tiles per iteration, LDS 128KB:
//   buf0 = even K-tiles, buf1 = odd K-tiles; each buf: A[256][64] + B[256][64]
// T2 swizzle: physical colByte = logical colByte ^ ((row&7)<<4), applied via
// pre-swizzled GLOBAL source (global_load_lds writes linearly) + swizzled read.
// =====================================================================
__launch_bounds__(512, 2)
__global__ void gemm256(const unsigned short* __restrict__ xb,
                        const unsigned short* __restrict__ wb,
                        const float* __restrict__ bias,
                        float* __restrict__ out, int s0, int nwg) {
    __shared__ __align__(16) char smem[131072];
    const int tid = threadIdx.x;
    const int l   = tid & 63;
    const int w   = tid >> 6;    // 0..7
    const int wr  = w >> 2;      // 0..1  (M half)
    const int wc  = w & 3;       // 0..3  (N quarter)

    // T1: XCD-aware bijective swizzle (nwg = 64*sc, always % 8 == 0)
    const int b   = blockIdx.x;
    const int q8  = nwg >> 3;
    const int g   = (b & 7) * q8 + (b >> 3);
    const int mi  = g & 15;      // M fastest -> consecutive blocks share B-panel
    const int ni  = g >> 4;
    const int m0  = mi * 256;
    const int n0  = ni * 256;    // within-chunk N offset

    // staging lane geometry: each gload16 covers 8 rows x 128B; lane l writes
    // LDS row srow=l>>3, phys slot (l&7)*16 -> must source logical col
    // ((l&7)^srow)*16 bytes (the swizzle involution).
    const int srow = l >> 3;
    const int scol = ((l & 7) ^ srow) * 8;            // element offset
    const size_t slane = (size_t)srow * NIN + scol;

    // ds_read lane geometry (16x16x32 frag): row += lane&15, logical colByte
    // = kk*64 + (lane>>4)*16; physical = logical ^ ((lane&7)<<4).
    const int rowp  = (l & 15) * 128;
    const int colp0 = ((l >> 4) ^ (l & 7)) << 4;

    f32x4 acc[8][4] = {};
    bf16x8 aF[4][2], b0F[2][2], b1F[2][2];

    const unsigned short* xbase = xb + (size_t)m0 * NIN;
    const unsigned short* wbase = wb + (size_t)n0 * NIN;

    auto STAGE = [&](int buf, int kt, int q) {
        const int R = (q & 3) * 64 + w * 8;           // unit start row
        const unsigned short* src = ((q < 4) ? xbase : wbase)
                                    + (size_t)R * NIN + kt * 64 + slane;
        char* dst = smem + buf * 65536 + ((q >= 4) ? 32768 : 0) + R * 128;
        gload16(src, dst);
    };

    auto LDA = [&](int buf, int mh) {
        const char* base = smem + buf * 65536 + (wr * 128 + mh * 64) * 128 + rowp;
        #pragma unroll
        for (int mb = 0; mb < 4; ++mb) {
            aF[mb][0] = *(const bf16x8*)(base + mb * 2048 + colp0);
            aF[mb][1] = *(const bf16x8*)(base + mb * 2048 + (colp0 ^ 64));
        }
    };
    auto LDB = [&](bf16x8 (&bF)[2][2], int buf, int nh) {
        const char* base = smem + buf * 65536 + 32768 + (wc * 64 + nh * 32) * 128 + rowp;
        #pragma unroll
        for (int nb = 0; nb < 2; ++nb) {
            bF[nb][0] = *(const bf16x8*)(base + nb * 2048 + colp0);
            bF[nb][1] = *(const bf16x8*)(base + nb * 2048 + (colp0 ^ 64));
        }
    };

    auto MM = [&](auto MHc, auto NHc, bf16x8 (&bF)[2][2]) {
        constexpr int MH = decltype(MHc)::value;
        constexpr int NH = decltype(NHc)::value;
        __builtin_amdgcn_s_setprio(1);
        #pragma unroll
        for (int mb = 0; mb < 4; ++mb)
            #pragma unroll
            for (int nb = 0; nb < 2; ++nb)
                #pragma unroll
                for (int kk = 0; kk < 2; ++kk)
                    acc[MH * 4 + mb][NH * 2 + nb] = __builtin_amdgcn_mfma_f32_16x16x32_bf16(
                        aF[mb][kk], bF[nb][kk], acc[MH * 4 + mb][NH * 2 + nb], 0, 0, 0);
        __builtin_amdgcn_s_setprio(0);
    };

    auto C0 = std::integral_constant<int, 0>{};
    auto C1 = std::integral_constant<int, 1>{};

    // One iteration = 8 phases over K-tiles (t0=2i in buf0, t1=2i+1 in buf1).
    // Stage ledger (per phase, 2 loads/thread):
    //   p0..p2: t1 q2..7 -> buf1 ;  p3..p6: t2 q0..7 -> buf0 ; p7: t3 q0,1 -> buf1
    // vmcnt(2) at p3 end (t1 fully landed) and p7 end (t2 fully landed).
    auto ITER = [&](auto LASTc, int t1, int t2, int t3) {
        constexpr bool LAST = decltype(LASTc)::value;
        // p0: reads buf0 A0,B0 ; MFMA (0,0)
        LDA(0, 0); LDB(b0F, 0, 0);
        STAGE(1, t1, 2); STAGE(1, t1, 3);
        BAR; LGK0; MM(C0, C0, b0F); BAR;
        // p1: read B1 ; MFMA (0,1)
        LDB(b1F, 0, 1);
        STAGE(1, t1, 4); STAGE(1, t1, 5);
        BAR; LGK0; MM(C0, C1, b1F); BAR;
        // p2: read A1 ; MFMA (1,1)   [last ds_read of buf0]
        LDA(0, 1);
        STAGE(1, t1, 6); STAGE(1, t1, 7);
        BAR; LGK0; MM(C1, C1, b1F); BAR;
        // p3: MFMA (1,0) ; vmcnt gate for buf1 reads
        if constexpr (!LAST) { STAGE(0, t2, 0); STAGE(0, t2, 1); }
        BAR; MM(C1, C0, b0F);
        if constexpr (LAST) { VMW0; } else { VMW2; }
        BAR;
        // p4: reads buf1 A0,B0 ; MFMA (0,0)
        LDA(1, 0); LDB(b0F, 1, 0);
        if constexpr (!LAST) { STAGE(0, t2, 2); STAGE(0, t2, 3); }
        BAR; LGK0; MM(C0, C0, b0F); BAR;
        // p5
        LDB(b1F, 1, 1);
        if constexpr (!LAST) { STAGE(0, t2, 4); STAGE(0, t2, 5); }
        BAR; LGK0; MM(C0, C1, b1F); BAR;
        // p6   [last ds_read of buf1]
        LDA(1, 1);
        if constexpr (!LAST) { STAGE(0, t2, 6); STAGE(0, t2, 7); }
        BAR; LGK0; MM(C1, C1, b1F); BAR;
        // p7
        if constexpr (!LAST) {
            STAGE(1, t3, 0); STAGE(1, t3, 1);
            BAR; MM(C1, C0, b0F); VMW2; BAR;
        } else {
            MM(C1, C0, b0F);
        }
    };

    // prologue: tile 0 -> buf0 (8 loads), tile 1 q0,1 -> buf1 ; wait tile0
    #pragma unroll
    for (int q = 0; q < 8; ++q) STAGE(0, 0, q);
    STAGE(1, 1, 0); STAGE(1, 1, 1);
    VMW2; BAR;

    #pragma unroll 1
    for (int i = 0; i < 7; ++i)
        ITER(std::false_type{}, 2 * i + 1, 2 * i + 2, 2 * i + 3);
    ITER(std::true_type{}, 15, 16, 17);

    // epilogue: bias + store. C/D map (verified r0): col=lane&15, row=(lane>>4)*4+reg
    const int s    = s0 + (n0 >> 10);
    const int csel = n0 & 1023;
    const int oc   = csel + wc * 64 + (l & 15);
    float bv[4];
    #pragma unroll
    for (int nb = 0; nb < 4; ++nb) bv[nb] = bias[s * NOUT + oc + nb * 16];
    float* outp = out + (size_t)s * NB * NOUT;
    #pragma unroll
    for (int mb = 0; mb < 8; ++mb) {
        #pragma unroll
        for (int i2 = 0; i2 < 4; ++i2) {
            int row = m0 + wr * 128 + mb * 16 + (l >> 4) * 4 + i2;
            float* rp = outp + (size_t)row * NOUT + oc;
            #pragma unroll
            for (int nb = 0; nb < 4; ++nb)
                rp[nb * 16] = acc[mb][nb][i2] + bv[nb];
        }
    }
}

// ---- zero-scratch correctness fallback (only if ws_size is tiny) ----
__global__ void fused_fallback(const float* __restrict__ x, const float* __restrict__ wmu,
                               const float* __restrict__ wls, const float* __restrict__ r1,
                               const float* __restrict__ bmu, const float* __restrict__ bls,
                               const float* __restrict__ r2, float* __restrict__ out) {
    __shared__ float Xs[16][64];
    __shared__ float Ws[16][64];
    int b0 = blockIdx.x * 16, o0 = blockIdx.y * 16, s = blockIdx.z;
    int tb = threadIdx.x >> 4, to = threadIdx.x & 15;
    float acc = 0.f;
    for (int k0 = 0; k0 < NIN; k0 += 64) {
        __syncthreads();
        #pragma unroll
        for (int j = 0; j < 4; ++j) {
            int e = j * 256 + threadIdx.x;
            int r = e >> 6, cc = e & 63;
            Xs[r][cc] = x[(size_t)(b0 + r) * NIN + k0 + cc];
            size_t wi = (size_t)(o0 + r) * NIN + k0 + cc;
            Ws[r][cc] = wmu[wi] + __expf(wls[wi]) * r1[(size_t)s * NIN * NOUT + wi];
        }
        __syncthreads();
        for (int k = 0; k < 64; ++k) acc += Xs[tb][k] * Ws[to][k];
    }
    int o = o0 + to;
    out[((size_t)s * NB + b0 + tb) * NOUT + o] = acc + bmu[o] + __expf(bls[o]) * r2[s * NOUT + o];
}

extern "C" void kernel_launch(void* const* d_in, const int* in_sizes, int n_in,
                              void* d_out, int out_size, void* d_ws, size_t ws_size,
                              hipStream_t stream) {
    const float* x   = (const float*)d_in[0];
    const float* wmu = (const float*)d_in[1];
    const float* wls = (const float*)d_in[2];
    const float* bmu = (const float*)d_in[3];
    const float* bls = (const float*)d_in[4];
    const float* r1  = (const float*)d_in[5];
    const float* r2  = (const float*)d_in[6];
    const int S = in_sizes[6] / NOUT;   // N_samples from r2 size
    float* out = (float*)d_out;

    size_t xb_bytes   = (size_t)NB * NIN * 2;
    size_t bias_bytes = (size_t)S * NOUT * 4;
    size_t per_sample = (size_t)NOUT * NIN * 2;

    if (ws_size < xb_bytes + bias_bytes + per_sample) {
        dim3 g(NB / 16, NOUT / 16, S);
        fused_fallback<<<g, 256, 0, stream>>>(x, wmu, wls, r1, bmu, bls, r2, out);
        return;
    }

    char* ws = (char*)d_ws;
    unsigned short* xb  = (unsigned short*)ws;
    float* bias         = (float*)(ws + xb_bytes);
    unsigned short* wb  = (unsigned short*)(ws + xb_bytes + bias_bytes);

    size_t avail = ws_size - xb_bytes - bias_bytes;
    int SC = (int)(avail / per_sample);
    if (SC > S) SC = S;

    cvt_x_kernel<<<NB * NIN / 4 / 256, 256, 0, stream>>>(x, xb);
    bias_kernel<<<(S * NOUT + 255) / 256, 256, 0, stream>>>(bmu, bls, r2, bias, S * NOUT);

    for (int s0 = 0; s0 < S; s0 += SC) {
        int sc = (S - s0 < SC) ? (S - s0) : SC;
        build_w_kernel<<<sc * (NOUT * NIN / 4 / 256), 256, 0, stream>>>(wmu, wls, r1, wb, s0);
        int nwg = 16 * sc * 4;   // (NB/256) * (sc*1024/256), always % 8 == 0
        gemm256<<<nwg, 512, 0, stream>>>(xb, wb, bias, out, s0, nwg);
    }
}